// Round 10
// baseline (1915.090 us; speedup 1.0000x reference)
//
#include <hip/hip_runtime.h>
#include <math.h>

// ComplexPolarTransformerBeta — round 10: 2 blocks/CU.
// R8/R9 plateau (~1000us) = 1 block/CU, 1 wave/SIMD -> all latency paid
// serially. Fix: shrink LDS 143->73.7KB so 2 blocks co-reside (8 waves/CU).
// Split-3 hi/lo planes are TIME-MULTIPLEXED: weight GEMMs read act-hi from R1
// + act-lo from R2 (weight hi/lo from global); attention GEMMs run 3
// single-plane passes (hh, hl, lh) with restages from producers' live accs.
// Bias uses R1 as fp32 [128][64] in 2 passes before mag staging. 256 thr
// (VGPR law: 65536/256=256), no prefetch (R9's spilled), lgkm-only barriers.

typedef __attribute__((ext_vector_type(8)))  short s16x8;
typedef __attribute__((ext_vector_type(16))) float f32x16;

#define STR  136      // LDS row stride in shorts (272B, 16B-aligned rows)
#define MFMA(a, b, c) __builtin_amdgcn_mfma_f32_32x32x16_bf16(a, b, c, 0, 0, 0)
#define ROWP(reg) (((reg) & 3) + (((reg) >> 2) << 3) + (h5 << 2))
#define BAR() asm volatile("s_waitcnt lgkmcnt(0)\n\ts_barrier" ::: "memory")

__device__ __forceinline__ unsigned short bfhi(float x) {
  unsigned u = __float_as_uint(x);
  return (unsigned short)((u + 0x7FFFu + ((u >> 16) & 1u)) >> 16);
}
__device__ __forceinline__ float bf2f(unsigned short h) {
  return __uint_as_float(((unsigned)h) << 16);
}

// Stage hi-plane of one C-layout tile into S[row][colbase+8q+4h5] (b64 writes).
__device__ __forceinline__ void stageHi(short* S, const f32x16& acc, int row,
                                        int colbase, int h5, float scl) {
  #pragma unroll
  for (int q = 0; q < 4; ++q) {
    int col = colbase + 8 * q + 4 * h5;
    *(short4*)(S + row * STR + col) = make_short4(
        (short)bfhi(acc[4*q+0]*scl), (short)bfhi(acc[4*q+1]*scl),
        (short)bfhi(acc[4*q+2]*scl), (short)bfhi(acc[4*q+3]*scl));
  }
}
// Stage lo-plane (residual after bf16 hi rounding).
__device__ __forceinline__ void stageLo(short* S, const f32x16& acc, int row,
                                        int colbase, int h5, float scl) {
  #pragma unroll
  for (int q = 0; q < 4; ++q) {
    int col = colbase + 8 * q + 4 * h5;
    float v0 = acc[4*q+0]*scl, v1 = acc[4*q+1]*scl;
    float v2 = acc[4*q+2]*scl, v3 = acc[4*q+3]*scl;
    unsigned short h0 = bfhi(v0), h1 = bfhi(v1), h2 = bfhi(v2), h3 = bfhi(v3);
    *(short4*)(S + row * STR + col) = make_short4(
        (short)bfhi(v0 - bf2f(h0)), (short)bfhi(v1 - bf2f(h1)),
        (short)bfhi(v2 - bf2f(h2)), (short)bfhi(v3 - bf2f(h3)));
  }
}

// acc[tt] += Wfrag(m-tile)^ * act(BH=hi rows 32tt+l31, BL=lo). split-3.
__device__ __forceinline__ void gemmTW4(f32x16* acc, const short* W,
                                        const short* BH, const short* BL,
                                        int mtile, int kbN, int l31, int h5, int lane) {
  #pragma unroll 1
  for (int kb = 0; kb < kbN; ++kb) {
    const short* wp = W + (((mtile * 8 + kb) * 64 + lane) * 8);
    s16x8 wh = *(const s16x8*)wp;
    s16x8 wl = *(const s16x8*)(wp + 32768);
    int k0 = kb * 16 + 8 * h5;
    #pragma unroll
    for (int tt = 0; tt < 4; ++tt) {
      int br = 32 * tt + l31;
      s16x8 bh = *(const s16x8*)(BH + br * STR + k0);
      s16x8 bl = *(const s16x8*)(BL + br * STR + k0);
      acc[tt] = MFMA(wh, bh, acc[tt]);
      acc[tt] = MFMA(wh, bl, acc[tt]);
      acc[tt] = MFMA(wl, bh, acc[tt]);
    }
  }
}

// acc[tt] += act(AH=hi rows mblk+l31, AL=lo) * Wfrag(n-tile=tt). split-3.
__device__ __forceinline__ void gemmNW4(f32x16* acc, const short* AH, const short* AL,
                                        const short* W, int mblk, int l31, int h5, int lane) {
  int ar = mblk + l31;
  #pragma unroll 1
  for (int kb = 0; kb < 8; ++kb) {
    int k0 = kb * 16 + 8 * h5;
    s16x8 ah = *(const s16x8*)(AH + ar * STR + k0);
    s16x8 al = *(const s16x8*)(AL + ar * STR + k0);
    #pragma unroll
    for (int tt = 0; tt < 4; ++tt) {
      const short* wp = W + (((tt * 8 + kb) * 64 + lane) * 8);
      s16x8 wh = *(const s16x8*)wp;
      s16x8 wl = *(const s16x8*)(wp + 32768);
      acc[tt] = MFMA(ah, wh, acc[tt]);
      acc[tt] = MFMA(ah, wl, acc[tt]);
      acc[tt] = MFMA(al, wh, acc[tt]);
    }
  }
}

// Single-plane pass: acc[tt] += A(rows mblk+l31) * B(rows 32tt+l31)^T.
__device__ __forceinline__ void gemmP4(f32x16* acc, const short* A, const short* B,
                                       int mblk, int l31, int h5) {
  int ar = mblk + l31;
  #pragma unroll 1
  for (int kb = 0; kb < 8; ++kb) {
    int k0 = kb * 16 + 8 * h5;
    s16x8 a = *(const s16x8*)(A + ar * STR + k0);
    #pragma unroll
    for (int tt = 0; tt < 4; ++tt) {
      int br = 32 * tt + l31;
      s16x8 bb = *(const s16x8*)(B + br * STR + k0);
      acc[tt] = MFMA(a, bb, acc[tt]);
    }
  }
}

// ---------------- weight preprocessing: fp32 [k][h] -> frag-ordered bf16 hi/lo ----
__global__ __launch_bounds__(512)
void prep_kernel(const float* __restrict__ Wq, const float* __restrict__ Wk,
                 const float* __restrict__ Wvm, const float* __restrict__ Wvp,
                 const float* __restrict__ rp_W,
                 const float* __restrict__ emb_Wm, const float* __restrict__ emb_Wp,
                 short* __restrict__ ws) {
  int mid = blockIdx.x >> 2, hblk = blockIdx.x & 3;
  int kb = threadIdx.x >> 6, lane = threadIdx.x & 63;
  const float* src;
  int krows = 128;
  if (mid < 4)        src = Wq  + mid * 16384;
  else if (mid < 8)   src = Wk  + (mid - 4) * 16384;
  else if (mid < 12)  src = Wvm + (mid - 8) * 16384;
  else if (mid < 16)  src = Wvp + (mid - 12) * 16384;
  else if (mid == 16) src = rp_W;
  else if (mid == 17) src = rp_W + 16384;
  else if (mid == 18) { src = emb_Wm; krows = 19; }
  else                { src = emb_Wp; krows = 19; }
  int h = hblk * 32 + (lane & 31);
  int kbase = kb * 16 + ((lane >> 5) << 3);
  s16x8 H, L;
  #pragma unroll
  for (int j = 0; j < 8; ++j) {
    int k = kbase + j;
    float v = (k < krows) ? src[(size_t)k * 128 + h] : 0.f;
    unsigned short hi = bfhi(v);
    H[j] = (short)hi;
    L[j] = (short)bfhi(v - bf2f(hi));
  }
  short* dst = ws + (size_t)mid * 65536 + ((hblk * 8 + kb) * 64 + lane) * 8;
  *(s16x8*)dst = H;
  *(s16x8*)(dst + 32768) = L;
}

// ---------------- main kernel ----------------
__global__ __launch_bounds__(256, 2)
void cpt_kernel(const float* __restrict__ atom_types,
                const float* __restrict__ coords,
                const int*   __restrict__ edge_index,
                const float* __restrict__ edge_attr,
                const float* __restrict__ emb_bm, const float* __restrict__ emb_bp,
                const float* __restrict__ bq, const float* __restrict__ bk,
                const float* __restrict__ bvm, const float* __restrict__ bvp,
                const float* __restrict__ We,  const float* __restrict__ be,
                const float* __restrict__ dist_scale,
                const float* __restrict__ ln_g, const float* __restrict__ ln_b,
                const float* __restrict__ rp_b,
                const float* __restrict__ h1_W, const float* __restrict__ h1_b,
                const float* __restrict__ h2_W, const float* __restrict__ h2_b,
                const short* __restrict__ wpre,
                float* __restrict__ out)
{
  __shared__ __align__(16) short R1s[17408];   // one plane: 128 x STR shorts
  __shared__ __align__(16) short R2s[17408];
  __shared__ float SCa[512];
  __shared__ float SCb[512];

  const int t = threadIdx.x, b = blockIdx.x;
  const int w = t >> 6, lane = t & 63, l31 = lane & 31, h5 = lane >> 5;
  const int mblk = w << 5;
  const float scale = 0.08838834764831845f;  // 1/sqrt(128)

  // ---- edge gather (layer-invariant indices/attrs, 4 edges/thread) ----
  int e0i[4], e1i[4]; float4 eav[4];
  #pragma unroll
  for (int k = 0; k < 4; ++k) {
    int e = t + 256 * k;
    e0i[k] = edge_index[(size_t)b * 2048 + e];           // i (scores row)
    e1i[k] = edge_index[(size_t)b * 2048 + 1024 + e];    // j (scores col)
    eav[k] = *(const float4*)(edge_attr + ((size_t)b * 1024 + e) * 4);
  }

  // ---- stage x (atom_types||coords, k padded to 32): hi->R1, lo->R2 ----
  if (t < 128) {
    const float* xr = atom_types + ((size_t)b * 128 + t) * 16;
    const float* cr = coords + ((size_t)b * 128 + t) * 3;
    float xv[19];
    float4 a0 = *(const float4*)xr,       a1 = *(const float4*)(xr + 4);
    float4 a2 = *(const float4*)(xr + 8), a3 = *(const float4*)(xr + 12);
    xv[0]=a0.x; xv[1]=a0.y; xv[2]=a0.z; xv[3]=a0.w;
    xv[4]=a1.x; xv[5]=a1.y; xv[6]=a1.z; xv[7]=a1.w;
    xv[8]=a2.x; xv[9]=a2.y; xv[10]=a2.z; xv[11]=a2.w;
    xv[12]=a3.x; xv[13]=a3.y; xv[14]=a3.z; xv[15]=a3.w;
    xv[16]=cr[0]; xv[17]=cr[1]; xv[18]=cr[2];
    #pragma unroll
    for (int k = 0; k < 32; ++k) {
      float v = (k < 19) ? xv[k] : 0.f;
      unsigned short hh = bfhi(v);
      R1s[t * STR + k] = (short)hh;
      R2s[t * STR + k] = (short)bfhi(v - bf2f(hh));
    }
  }
  BAR();

  // ---- embedding via MFMA: magT/phT TRANSPOSED (h=32w+ROWP, a=32tt+l31) ----
  f32x16 magT[4], phT[4];
  #pragma unroll
  for (int reg = 0; reg < 16; ++reg) {
    float bm = emb_bm[32 * w + ROWP(reg)];
    float bp = emb_bp[32 * w + ROWP(reg)];
    #pragma unroll
    for (int tt = 0; tt < 4; ++tt) { magT[tt][reg] = bm; phT[tt][reg] = bp; }
  }
  gemmTW4(magT, wpre + (size_t)18 * 65536, R1s, R2s, w, 2, l31, h5, lane);
  gemmTW4(phT,  wpre + (size_t)19 * 65536, R1s, R2s, w, 2, l31, h5, lane);

  // ---- layers ----
  for (int l = 0; l < 4; ++l) {
    const short* wqP  = wpre + (size_t)l * 65536;
    const short* wkP  = wpre + (size_t)(4 + l) * 65536;
    const short* wvmP = wpre + (size_t)(8 + l) * 65536;
    const short* wvpP = wpre + (size_t)(12 + l) * 65536;
    float we0 = We[l*4], we1 = We[l*4+1], we2 = We[l*4+2], we3 = We[l*4+3];
    float bel = be[l], dsl = dist_scale[l];

    // --- edge bias -> accS, 2 passes of fp32 [128][64] in R1 ---
    f32x16 accS[4];
    float* R1f = (float*)R1s;
    #pragma unroll 1
    for (int p = 0; p < 2; ++p) {
      BAR();                               // prior readers of R1 done
      float4* z4 = (float4*)R1f;
      #pragma unroll
      for (int k = 0; k < 8; ++k) z4[t + 256 * k] = make_float4(0.f,0.f,0.f,0.f);
      BAR();
      #pragma unroll
      for (int k = 0; k < 4; ++k) {
        if ((e0i[k] >> 6) == p) {
          float bval = eav[k].x*we0 + eav[k].y*we1 + eav[k].z*we2 +
                       eav[k].w*we3 + bel + dsl*eav[k].x;
          atomicAdd(&R1f[e1i[k] * 64 + (e0i[k] & 63)], bval);
        }
      }
      BAR();
      #pragma unroll
      for (int th = 0; th < 2; ++th) {
        int tt = 2 * p + th;
        #pragma unroll
        for (int reg = 0; reg < 16; ++reg)
          accS[tt][reg] = R1f[(32 * w + ROWP(reg)) * 64 + 32 * th + l31];
      }
    }
    BAR();                                 // bias reads done
    // --- stage mag: hi->R1, lo->R2 ---
    #pragma unroll
    for (int tt = 0; tt < 4; ++tt) {
      stageHi(R1s, magT[tt], 32 * tt + l31, mblk, h5, 1.f);
      stageLo(R2s, magT[tt], 32 * tt + l31, mblk, h5, 1.f);
    }
    BAR();

    // --- Q^T, K^T (weight GEMMs, full split-3) ---
    f32x16 accQ[4], accK[4];
    #pragma unroll
    for (int reg = 0; reg < 16; ++reg) {
      float bvq = bq[l * 128 + 32 * w + ROWP(reg)];
      float bvk = bk[l * 128 + 32 * w + ROWP(reg)];
      #pragma unroll
      for (int tt = 0; tt < 4; ++tt) { accQ[tt][reg] = bvq; accK[tt][reg] = bvk; }
    }
    gemmTW4(accQ, wqP, R1s, R2s, w, 8, l31, h5, lane);
    gemmTW4(accK, wkP, R1s, R2s, w, 8, l31, h5, lane);
    BAR();                                 // mag reads done
    // --- scores: 3 single-plane passes ---
    #pragma unroll
    for (int tt = 0; tt < 4; ++tt) {
      stageHi(R1s, accK[tt], 32 * tt + l31, mblk, h5, 1.f);     // K_h
      stageHi(R2s, accQ[tt], 32 * tt + l31, mblk, h5, scale);   // Qs_h
    }
    BAR();
    gemmP4(accS, R1s, R2s, mblk, l31, h5);                      // K_h . Q_h
    BAR();
    #pragma unroll
    for (int tt = 0; tt < 4; ++tt)
      stageLo(R2s, accQ[tt], 32 * tt + l31, mblk, h5, scale);   // Qs_l
    BAR();
    gemmP4(accS, R1s, R2s, mblk, l31, h5);                      // K_h . Q_l
    BAR();
    #pragma unroll
    for (int tt = 0; tt < 4; ++tt) {
      stageLo(R1s, accK[tt], 32 * tt + l31, mblk, h5, 1.f);     // K_l
      stageHi(R2s, accQ[tt], 32 * tt + l31, mblk, h5, scale);   // Qs_h again
    }
    BAR();
    gemmP4(accS, R1s, R2s, mblk, l31, h5);                      // K_l . Q_h

    // --- fused softmax over j ---
    float mloc[4];
    #pragma unroll
    for (int tt = 0; tt < 4; ++tt) {
      float m = accS[tt][0];
      #pragma unroll
      for (int reg = 1; reg < 16; ++reg) m = fmaxf(m, accS[tt][reg]);
      m = fmaxf(m, __shfl_xor(m, 32));
      float s = 0.f;
      #pragma unroll
      for (int reg = 0; reg < 16; ++reg) {
        float e = __expf(accS[tt][reg] - m);
        accS[tt][reg] = e; s += e;
      }
      s += __shfl_xor(s, 32);
      mloc[tt] = m;
      if (h5 == 0) { SCa[w * 128 + 32 * tt + l31] = m; SCb[w * 128 + 32 * tt + l31] = s; }
    }
    BAR();
    #pragma unroll
    for (int tt = 0; tt < 4; ++tt) {
      int i = 32 * tt + l31;
      float m0 = SCa[i], m1 = SCa[128 + i], m2 = SCa[256 + i], m3 = SCa[384 + i];
      float mg = fmaxf(fmaxf(m0, m1), fmaxf(m2, m3));
      float sg = SCb[i] * __expf(m0 - mg) + SCb[128 + i] * __expf(m1 - mg) +
                 SCb[256 + i] * __expf(m2 - mg) + SCb[384 + i] * __expf(m3 - mg);
      float f = __expf(mloc[tt] - mg) / sg;
      #pragma unroll
      for (int reg = 0; reg < 16; ++reg) accS[tt][reg] *= f;     // accS = P
    }
    BAR();                                 // scores reads of R1/R2 done

    // --- vm = mag @ Wvm ---
    #pragma unroll
    for (int tt = 0; tt < 4; ++tt) {
      stageHi(R1s, magT[tt], 32 * tt + l31, mblk, h5, 1.f);
      stageLo(R2s, magT[tt], 32 * tt + l31, mblk, h5, 1.f);
    }
    BAR();
    f32x16 accVM[4];
    #pragma unroll
    for (int tt = 0; tt < 4; ++tt) {
      float bv = bvm[l * 128 + 32 * tt + l31];
      #pragma unroll
      for (int reg = 0; reg < 16; ++reg) accVM[tt][reg] = bv;
    }
    gemmNW4(accVM, R1s, R2s, wvmP, mblk, l31, h5, lane);
    BAR();                                 // mag reads done
    // --- AV1: 3 passes ---
    #pragma unroll
    for (int tt = 0; tt < 4; ++tt) {
      stageHi(R1s, accVM[tt], 32 * tt + l31, mblk, h5, 1.f);    // vmT_h
      stageHi(R2s, accS[tt], 32 * tt + l31, mblk, h5, 1.f);     // P_h
    }
    BAR();
    f32x16 accM[4];
    #pragma unroll
    for (int tt = 0; tt < 4; ++tt) accM[tt] = magT[tt];
    gemmP4(accM, R1s, R2s, mblk, l31, h5);                      // vm_h . P_h
    BAR();
    #pragma unroll
    for (int tt = 0; tt < 4; ++tt)
      stageLo(R2s, accS[tt], 32 * tt + l31, mblk, h5, 1.f);     // P_l
    BAR();
    gemmP4(accM, R1s, R2s, mblk, l31, h5);                      // vm_h . P_l
    BAR();
    #pragma unroll
    for (int tt = 0; tt < 4; ++tt) {
      stageLo(R1s, accVM[tt], 32 * tt + l31, mblk, h5, 1.f);    // vmT_l
      stageHi(R2s, accS[tt], 32 * tt + l31, mblk, h5, 1.f);     // P_h
    }
    BAR();
    gemmP4(accM, R1s, R2s, mblk, l31, h5);                      // vm_l . P_h

    // --- LayerNorm over h -> magT ---
    #pragma unroll
    for (int tt = 0; tt < 4; ++tt) {
      float s = 0.f, q = 0.f;
      #pragma unroll
      for (int reg = 0; reg < 16; ++reg) { float v = accM[tt][reg]; s += v; q += v*v; }
      s += __shfl_xor(s, 32); q += __shfl_xor(q, 32);
      if (h5 == 0) { SCa[w * 128 + 32 * tt + l31] = s; SCb[w * 128 + 32 * tt + l31] = q; }
    }
    BAR();
    #pragma unroll
    for (int reg = 0; reg < 16; ++reg) {
      float gv = ln_g[l * 128 + 32 * w + ROWP(reg)];
      float bv = ln_b[l * 128 + 32 * w + ROWP(reg)];
      #pragma unroll
      for (int tt = 0; tt < 4; ++tt) {
        int i = 32 * tt + l31;
        float s = SCa[i] + SCa[128 + i] + SCa[256 + i] + SCa[384 + i];
        float q = SCb[i] + SCb[128 + i] + SCb[256 + i] + SCb[384 + i];
        float mu = s * (1.f / 128.f);
        float var = q * (1.f / 128.f) - mu * mu;
        float inv = 1.f / sqrtf(var + 1e-5f);
        magT[tt][reg] = gv * ((accM[tt][reg] - mu) * inv) + bv;
      }
    }
    BAR();                                 // AV1 reads done

    // --- vp = ph @ Wvp ---
    #pragma unroll
    for (int tt = 0; tt < 4; ++tt) {
      stageHi(R1s, phT[tt], 32 * tt + l31, mblk, h5, 1.f);
      stageLo(R2s, phT[tt], 32 * tt + l31, mblk, h5, 1.f);
    }
    BAR();
    f32x16 accV[4];
    #pragma unroll
    for (int tt = 0; tt < 4; ++tt) {
      float bv = bvp[l * 128 + 32 * tt + l31];
      #pragma unroll
      for (int reg = 0; reg < 16; ++reg) accV[tt][reg] = bv;
    }
    gemmNW4(accV, R1s, R2s, wvpP, mblk, l31, h5, lane);
    BAR();                                 // ph reads done
    // --- AV2: 3 passes ---
    #pragma unroll
    for (int tt = 0; tt < 4; ++tt) {
      stageHi(R1s, accV[tt], 32 * tt + l31, mblk, h5, 1.f);     // vpT_h
      stageHi(R2s, accS[tt], 32 * tt + l31, mblk, h5, 1.f);     // P_h
    }
    BAR();
    f32x16 accP[4];
    #pragma unroll
    for (int tt = 0; tt < 4; ++tt) accP[tt] = phT[tt];
    gemmP4(accP, R1s, R2s, mblk, l31, h5);                      // vp_h . P_h
    BAR();
    #pragma unroll
    for (int tt = 0; tt < 4; ++tt)
      stageLo(R2s, accS[tt], 32 * tt + l31, mblk, h5, 1.f);     // P_l
    BAR();
    gemmP4(accP, R1s, R2s, mblk, l31, h5);                      // vp_h . P_l
    BAR();
    #pragma unroll
    for (int tt = 0; tt < 4; ++tt) {
      stageLo(R1s, accV[tt], 32 * tt + l31, mblk, h5, 1.f);     // vpT_l
      stageHi(R2s, accS[tt], 32 * tt + l31, mblk, h5, 1.f);     // P_h
    }
    BAR();
    gemmP4(accP, R1s, R2s, mblk, l31, h5);                      // vp_l . P_h
    #pragma unroll
    for (int tt = 0; tt < 4; ++tt) phT[tt] = accP[tt];
    BAR();                                 // AV2 reads done
  } // layers

  // ---- real/imag -> RealProjection ----
  #pragma unroll
  for (int tt = 0; tt < 4; ++tt)
    #pragma unroll
    for (int reg = 0; reg < 16; ++reg) {
      float s_, c_;
      __sincosf(phT[tt][reg], &s_, &c_);
      float m = magT[tt][reg];
      magT[tt][reg] = m * c_;      // re
      phT[tt][reg]  = m * s_;      // im
    }
  #pragma unroll
  for (int tt = 0; tt < 4; ++tt) {
    stageHi(R1s, magT[tt], 32 * tt + l31, mblk, h5, 1.f);
    stageLo(R2s, magT[tt], 32 * tt + l31, mblk, h5, 1.f);
  }
  BAR();
  f32x16 accR[4];
  #pragma unroll
  for (int tt = 0; tt < 4; ++tt) {
    float bv = rp_b[32 * tt + l31];
    #pragma unroll
    for (int reg = 0; reg < 16; ++reg) accR[tt][reg] = bv;
  }
  gemmNW4(accR, R1s, R2s, wpre + (size_t)16 * 65536, mblk, l31, h5, lane);  // re @ rpA
  BAR();
  #pragma unroll
  for (int tt = 0; tt < 4; ++tt) {
    stageHi(R1s, phT[tt], 32 * tt + l31, mblk, h5, 1.f);
    stageLo(R2s, phT[tt], 32 * tt + l31, mblk, h5, 1.f);
  }
  BAR();
  gemmNW4(accR, R1s, R2s, wpre + (size_t)17 * 65536, mblk, l31, h5, lane);  // im @ rpB

  // ---- pooling: column sum over atoms (accR: m=a=mblk+ROWP, n=h=32tt+l31) ----
  #pragma unroll
  for (int tt = 0; tt < 4; ++tt) {
    float ps = 0.f;
    #pragma unroll
    for (int reg = 0; reg < 16; ++reg) ps += accR[tt][reg];
    ps += __shfl_xor(ps, 32);
    if (h5 == 0) SCa[w * 128 + 32 * tt + l31] = ps;
  }
  BAR();
  if (t < 128) {
    float cs = SCa[t] + SCa[128 + t] + SCa[256 + t] + SCa[384 + t];
    SCb[t] = cs;
  }
  BAR();
  if (t < 128) {
    float acc = h1_b[t];
    for (int i = 0; i < 128; ++i) {
      float c = SCb[i];
      acc += c * (h1_W[(size_t)i * 128 + t] * (1.f / 128.f) +
                  h1_W[(size_t)(128 + i) * 128 + t]);
    }
    float hv = acc / (1.f + __expf(-acc));   // SiLU
    SCa[t] = hv * h2_W[t];
  }
  BAR();
  if (t < 64) {
    float s2 = SCa[t] + SCa[64 + t];
    #pragma unroll
    for (int off = 32; off >= 1; off >>= 1) s2 += __shfl_xor(s2, off);
    if (t == 0) out[b] = s2 + h2_b[0];
  }
}

extern "C" void kernel_launch(void* const* d_in, const int* in_sizes, int n_in,
                              void* d_out, int out_size, void* d_ws, size_t ws_size,
                              hipStream_t stream) {
  const float* atom_types = (const float*)d_in[0];
  const float* coords     = (const float*)d_in[1];
  const int*   edge_index = (const int*)  d_in[2];
  const float* edge_attr  = (const float*)d_in[3];
  const float* emb_Wm = (const float*)d_in[4];
  const float* emb_bm = (const float*)d_in[5];
  const float* emb_Wp = (const float*)d_in[6];
  const float* emb_bp = (const float*)d_in[7];
  const float* Wq  = (const float*)d_in[8];
  const float* bq  = (const float*)d_in[9];
  const float* Wk  = (const float*)d_in[10];
  const float* bk  = (const float*)d_in[11];
  const float* Wvm = (const float*)d_in[12];
  const float* bvm = (const float*)d_in[13];
  const float* Wvp = (const float*)d_in[14];
  const float* bvp = (const float*)d_in[15];
  const float* We  = (const float*)d_in[16];
  const float* be  = (const float*)d_in[17];
  const float* dist_scale = (const float*)d_in[18];
  const float* ln_g = (const float*)d_in[19];
  const float* ln_b = (const float*)d_in[20];
  const float* rp_W = (const float*)d_in[21];
  const float* rp_b = (const float*)d_in[22];
  const float* h1_W = (const float*)d_in[23];
  const float* h1_b = (const float*)d_in[24];
  const float* h2_W = (const float*)d_in[25];
  const float* h2_b = (const float*)d_in[26];
  float* out = (float*)d_out;
  short* wpre = (short*)d_ws;   // 20 matrices * 131072 B = 2.62 MB

  hipLaunchKernelGGL(prep_kernel, dim3(80), dim3(512), 0, stream,
                     Wq, Wk, Wvm, Wvp, rp_W, emb_Wm, emb_Wp, wpre);
  hipLaunchKernelGGL(cpt_kernel, dim3(1024), dim3(256), 0, stream,
                     atom_types, coords, edge_index, edge_attr,
                     emb_bm, emb_bp,
                     bq, bk, bvm, bvp,
                     We, be, dist_scale, ln_g, ln_b,
                     rp_b, h1_W, h1_b, h2_W, h2_b,
                     (const short*)wpre, out);
}